// Round 10
// baseline (196.390 us; speedup 1.0000x reference)
//
#include <hip/hip_runtime.h>
#include <hip/hip_bf16.h>

// StyledConv: B=8, Cin=Cout=64, H=W=256, S=512, K=3
#define BB   8
#define CC   64
#define HH   256
#define WW   256
#define SS   512
#define HW   (HH*WW)

#define LIN_SCALE  0.044194173824159216f   // 1/sqrt(512)
#define CONV_SCALE 0.041666666666666664f   // 1/24
#define LRELU      0.2f
#define GAIN       1.4142135623730951f

// conv tile: 4 rows x 32 cols out, all 64 co, all 64 ci staged once
#define TY 4
#define TX 32
#define LY (TY + 2)   // 6
#define LX (TX + 2)   // 34

typedef __attribute__((ext_vector_type(8))) short short8;            // A/B frag (8 bf16)
typedef __attribute__((ext_vector_type(4))) float floatx4;           // C/D frag

static __device__ __forceinline__ unsigned short f2bf(float f) {
    unsigned u = __float_as_uint(f);
    u += 0x7FFF + ((u >> 16) & 1);          // RNE (inputs finite)
    return (unsigned short)(u >> 16);
}

// packed f32x2 -> bf16x2 (v_cvt_pk_bf16_f32)
static __device__ __forceinline__ unsigned pk2(float a, float b) {
    __hip_bfloat162 h = __float22bfloat162_rn(make_float2(a, b));
    return *(unsigned*)&h;
}

#define VC(vv,kk) ((kk)==0?(vv).x:((kk)==1?(vv).y:((kk)==2?(vv).z:(vv).w)))

// ---------------- Kernel A: s[b][ci] = style[b,:] @ mod_w[:,ci] * lin_scale + mod_b
__global__ void mod_kernel(const float* __restrict__ style,
                           const float* __restrict__ mod_w,
                           const float* __restrict__ mod_b,
                           float* __restrict__ s_out) {
    __shared__ float part[256];
    int b = blockIdx.x;
    int t = threadIdx.x;
    int ci = t & 63, kp = t >> 6;
    const float* st = style + b * SS + kp * 128;
    float acc = 0.f;
    for (int k = 0; k < 128; ++k)
        acc = fmaf(st[k], mod_w[(kp * 128 + k) * CC + ci], acc);
    part[t] = acc;
    __syncthreads();
    if (t < 64) {
        float v = part[t] + part[t + 64] + part[t + 128] + part[t + 192];
        s_out[b * CC + t] = v * LIN_SCALE + mod_b[t];
    }
}

// ---------------- Kernel B: modulate + demod (f32), bf16 weights in A-frag layout
// wbf[b][ko 9][cic 2][cg 4][co 64][j 8]   (ci = cic*32 + cg*8 + j)
__global__ void wmod_kernel(const float* __restrict__ weight,
                            const float* __restrict__ s_in,
                            unsigned short* __restrict__ wbf) {
    int bc = blockIdx.x;                // b*64 + co
    int b = bc >> 6, co = bc & 63;
    int ci = threadIdx.x;               // one wave
    float wv[9];
    float sv = s_in[b * CC + ci] * CONV_SCALE;
    float sum = 0.f;
    const float* wp = weight + (co * CC + ci) * 9;
#pragma unroll
    for (int k = 0; k < 9; ++k) {
        wv[k] = wp[k] * sv;
        sum = fmaf(wv[k], wv[k], sum);
    }
#pragma unroll
    for (int off = 32; off; off >>= 1)
        sum += __shfl_xor(sum, off);
    float demod = rsqrtf(sum + 1e-8f);
    int cic = ci >> 5, cg = (ci >> 3) & 3, j = ci & 7;
#pragma unroll
    for (int ko = 0; ko < 9; ++ko) {
        size_t idx = (((((size_t)b * 9 + ko) * 2 + cic) * 4 + cg) * 64 + co) * 8 + j;
        wbf[idx] = f2bf(wv[ko] * demod);
    }
}

// ---------------- Kernel C: implicit-GEMM conv, MFMA 16x16x32 bf16
// 256 thr (4 waves). Wave wv owns co-group wv*16..+15 and ALL 128 px (8 N-tiles).
// A-frags (18 short8 = 72 VGPR) loaded after the barrier and PINNED in registers
// via sched_barrier(0) below the load block; inner loop = pure ds_read_b128+MFMA.
// LDS [6][34][64] bf16 (25.5 KB), swizzle byte ^= (lx&7)<<4.
__global__ __launch_bounds__(256, 3) void conv_kernel(
        const float* __restrict__ x,
        const float* __restrict__ noise,
        const float* __restrict__ nwp,
        const float* __restrict__ bias,
        const unsigned short* __restrict__ wbf,
        float* __restrict__ out) {
    __shared__ unsigned short xs[LY * LX * 64];   // 26112 B

    // bijective XCD swizzle: XCD c -> batch image b=c (512 blocks per image)
    const int lin  = blockIdx.x;                 // 0..4095
    const int lin2 = (lin & 7) * 512 + (lin >> 3);
    const int b   = lin2 >> 9;
    const int rem = lin2 & 511;
    const int by  = rem >> 3;      // 0..63
    const int bx  = rem & 7;       // 0..7
    const int x0t = bx * TX;
    const int y0t = by * TY;

    const int t = threadIdx.x;
    const int lane = t & 63;
    const int wv = t >> 6;         // wave 0..3 -> co-group
    const int l15 = lane & 15;
    const int cg = lane >> 4;      // 0..3

    // ---- stage: 480 tasks (yl 6, q 10, cig 8), branchless (clamped loads)
#pragma unroll
    for (int it = 0; it < 2; ++it) {
        int n = t + it * 256;
        n = n < 479 ? n : 479;
        int cig = n & 7;
        int m = n >> 3;
        int q = m % 10;
        int yl = m / 10;            // 0..5
        int gy = y0t + yl - 1;      // -1..256
        int gx0 = x0t - 4 + q * 4;  // -4..256, 4-aligned
        bool rowok = (unsigned)gy < (unsigned)HH;
        int gyc  = gy < 0 ? 0 : (gy > HH - 1 ? HH - 1 : gy);
        int gx0c = gx0 < 0 ? 0 : (gx0 > WW - 4 ? WW - 4 : gx0);
        const float* xp = x + ((size_t)b * CC + cig * 8) * HW + (size_t)gyc * WW + gx0c;
        float4 v[8];
#pragma unroll
        for (int j = 0; j < 8; ++j)
            v[j] = *(const float4*)(xp + (size_t)j * HW);
#pragma unroll
        for (int k = 0; k < 4; ++k) {
            int lx = 4 * q - 3 + k;
            if ((unsigned)lx < (unsigned)LX) {
                bool ok = rowok && ((unsigned)(gx0 + k) < (unsigned)WW);
                uint4 w;
                w.x = ok ? pk2(VC(v[0], k), VC(v[1], k)) : 0u;
                w.y = ok ? pk2(VC(v[2], k), VC(v[3], k)) : 0u;
                w.z = ok ? pk2(VC(v[4], k), VC(v[5], k)) : 0u;
                w.w = ok ? pk2(VC(v[6], k), VC(v[7], k)) : 0u;
                unsigned off = ((unsigned)((yl * LX + lx) * 64 + cig * 8) * 2)
                               ^ ((unsigned)(lx & 7) << 4);
                *(uint4*)((char*)xs + off) = w;
            }
        }
    }
    __syncthreads();
    __builtin_amdgcn_sched_barrier(0);   // A-loads stay below the stage phase

    // ---- A-frags to registers: a[cic*9+ko], co = wv*16 + l15, k-slice cg*8..+7
    short8 a[18];
    {
        const unsigned short* wbase = wbf + (size_t)b * (9 * 2 * 4 * 64 * 8);
#pragma unroll
        for (int cic = 0; cic < 2; ++cic)
#pragma unroll
            for (int ko = 0; ko < 9; ++ko)
                a[cic * 9 + ko] = *(const short8*)(wbase +
                    ((((ko * 2 + cic) * 4 + cg) * 64) + wv * 16 + l15) * 8);
    }
    __builtin_amdgcn_sched_barrier(0);   // PIN: loads cannot sink into the loop

    // ---- compute: pure LDS + MFMA. 18 K-chunks x 8 N-tiles.
    floatx4 acc[8];
#pragma unroll
    for (int nt = 0; nt < 8; ++nt) acc[nt] = (floatx4)0.f;

#pragma unroll
    for (int cic = 0; cic < 2; ++cic) {
#pragma unroll
        for (int kh = 0; kh < 3; ++kh) {
#pragma unroll
            for (int kw = 0; kw < 3; ++kw) {
                const short8 av = a[cic * 9 + kh * 3 + kw];
#pragma unroll
                for (int nt = 0; nt < 8; ++nt) {
                    int r = nt >> 1, h = nt & 1;
                    int ys = r + kh;
                    int xl = h * 16 + l15 + kw;
                    unsigned off = ((unsigned)((ys * LX + xl) * 64 + cic * 32 + cg * 8) * 2)
                                   ^ ((unsigned)(xl & 7) << 4);
                    short8 bfr = *(const short8*)((const char*)xs + off);
                    acc[nt] = __builtin_amdgcn_mfma_f32_16x16x32_bf16(
                        av, bfr, acc[nt], 0, 0, 0);
                }
            }
        }
    }

    // ---- epilogue: noise + bias + leaky_relu * gain
    float nw = nwp[0];
    float bv[4];
#pragma unroll
    for (int j = 0; j < 4; ++j) bv[j] = bias[wv * 16 + cg * 4 + j];

#pragma unroll
    for (int nt = 0; nt < 8; ++nt) {
        int r = nt >> 1, h = nt & 1;
        int py = y0t + r;
        int px = x0t + h * 16 + l15;
        float nz = nw * noise[(size_t)b * HW + (size_t)py * WW + px];
#pragma unroll
        for (int j = 0; j < 4; ++j) {
            int co = wv * 16 + cg * 4 + j;
            float vv = acc[nt][j] + nz + bv[j];
            vv = (vv > 0.f ? vv : LRELU * vv) * GAIN;
            out[((size_t)b * CC + co) * HW + (size_t)py * WW + px] = vv;
        }
    }
}

extern "C" void kernel_launch(void* const* d_in, const int* in_sizes, int n_in,
                              void* d_out, int out_size, void* d_ws, size_t ws_size,
                              hipStream_t stream) {
    const float* x       = (const float*)d_in[0];
    const float* style   = (const float*)d_in[1];
    const float* noise   = (const float*)d_in[2];
    const float* weight  = (const float*)d_in[3];
    const float* mod_w   = (const float*)d_in[4];
    const float* mod_b   = (const float*)d_in[5];
    const float* nw      = (const float*)d_in[6];
    const float* bias    = (const float*)d_in[7];
    float* out = (float*)d_out;

    float* s_buf          = (float*)d_ws;                          // 2 KB
    unsigned short* wbf   = (unsigned short*)((char*)d_ws + 4096); // 576 KB

    mod_kernel<<<dim3(BB), dim3(256), 0, stream>>>(style, mod_w, mod_b, s_buf);
    wmod_kernel<<<dim3(BB * CC), dim3(CC), 0, stream>>>(weight, s_buf, wbf);
    conv_kernel<<<dim3((WW / TX) * (HH / TY) * BB), dim3(256), 0, stream>>>(
        x, noise, nw, bias, wbf, out);
}

// Round 11
// 102.572 us; speedup vs baseline: 1.9147x; 1.9147x over previous
//
#include <hip/hip_runtime.h>
#include <hip/hip_bf16.h>

// StyledConv: B=8, Cin=Cout=64, H=W=256, S=512, K=3
#define BB   8
#define CC   64
#define HH   256
#define WW   256
#define SS   512
#define HW   (HH*WW)

#define LIN_SCALE  0.044194173824159216f   // 1/sqrt(512)
#define CONV_SCALE 0.041666666666666664f   // 1/24
#define LRELU      0.2f
#define GAIN       1.4142135623730951f

// conv tile: 4 rows x 32 cols out, all 64 co, all 64 ci staged once
#define TY 4
#define TX 32
#define LY (TY + 2)   // 6
#define LX (TX + 2)   // 34

typedef __attribute__((ext_vector_type(8))) short short8;            // A/B frag (8 bf16)
typedef __attribute__((ext_vector_type(4))) float floatx4;           // C/D frag

static __device__ __forceinline__ unsigned short f2bf(float f) {
    unsigned u = __float_as_uint(f);
    u += 0x7FFF + ((u >> 16) & 1);          // RNE (inputs finite)
    return (unsigned short)(u >> 16);
}

// packed f32x2 -> bf16x2 (v_cvt_pk_bf16_f32)
static __device__ __forceinline__ unsigned pk2(float a, float b) {
    __hip_bfloat162 h = __float22bfloat162_rn(make_float2(a, b));
    return *(unsigned*)&h;
}

#define VC(vv,kk) ((kk)==0?(vv).x:((kk)==1?(vv).y:((kk)==2?(vv).z:(vv).w)))

// ---------------- Kernel A: s[b][ci] = style[b,:] @ mod_w[:,ci] * lin_scale + mod_b
__global__ void mod_kernel(const float* __restrict__ style,
                           const float* __restrict__ mod_w,
                           const float* __restrict__ mod_b,
                           float* __restrict__ s_out) {
    __shared__ float part[256];
    int b = blockIdx.x;
    int t = threadIdx.x;
    int ci = t & 63, kp = t >> 6;
    const float* st = style + b * SS + kp * 128;
    float acc = 0.f;
    for (int k = 0; k < 128; ++k)
        acc = fmaf(st[k], mod_w[(kp * 128 + k) * CC + ci], acc);
    part[t] = acc;
    __syncthreads();
    if (t < 64) {
        float v = part[t] + part[t + 64] + part[t + 128] + part[t + 192];
        s_out[b * CC + t] = v * LIN_SCALE + mod_b[t];
    }
}

// ---------------- Kernel B: modulate + demod (f32), bf16 weights in A-frag layout
// wbf[b][ko 9][cic 2][cg 4][co 64][j 8]   (ci = cic*32 + cg*8 + j)
// For fixed (b,ko) the slice is 4096 contiguous elems (8 KB).
__global__ void wmod_kernel(const float* __restrict__ weight,
                            const float* __restrict__ s_in,
                            unsigned short* __restrict__ wbf) {
    int bc = blockIdx.x;                // b*64 + co
    int b = bc >> 6, co = bc & 63;
    int ci = threadIdx.x;               // one wave
    float wv[9];
    float sv = s_in[b * CC + ci] * CONV_SCALE;
    float sum = 0.f;
    const float* wp = weight + (co * CC + ci) * 9;
#pragma unroll
    for (int k = 0; k < 9; ++k) {
        wv[k] = wp[k] * sv;
        sum = fmaf(wv[k], wv[k], sum);
    }
#pragma unroll
    for (int off = 32; off; off >>= 1)
        sum += __shfl_xor(sum, off);
    float demod = rsqrtf(sum + 1e-8f);
    int cic = ci >> 5, cg = (ci >> 3) & 3, j = ci & 7;
#pragma unroll
    for (int ko = 0; ko < 9; ++ko) {
        size_t idx = (((((size_t)b * 9 + ko) * 2 + cic) * 4 + cg) * 64 + co) * 8 + j;
        wbf[idx] = f2bf(wv[ko] * demod);
    }
}

// ---------------- Kernel C: implicit-GEMM conv, MFMA 16x16x32 bf16
// 256 thr (4 waves). Wave wv owns co-group wv*16..+15 and ALL 128 px (8 N-tiles).
// 3 kh-phases: stage 24 KB of weights (3 kw-taps) into wlds, barrier, compute.
// Inner loop is PURE LDS: 1 A-frag ds_read + 8 B-frag ds_reads per (kw,cic).
// Only acc (32 VGPR) lives across phases -> no spill pressure.
// xs [6][34][64] bf16 (25.5 KB, swizzle byte ^= (lx&7)<<4) + wlds 24 KB = 50.7 KB.
__global__ __launch_bounds__(256, 3) void conv_kernel(
        const float* __restrict__ x,
        const float* __restrict__ noise,
        const float* __restrict__ nwp,
        const float* __restrict__ bias,
        const unsigned short* __restrict__ wbf,
        float* __restrict__ out) {
    __shared__ unsigned short xs[LY * LX * 64];      // 26112 B
    __shared__ unsigned short wlds[3 * 2 * 4 * 64 * 8];  // 12288 elems = 24576 B

    // bijective XCD swizzle: XCD c -> batch image b=c (512 blocks per image)
    const int lin  = blockIdx.x;                 // 0..4095
    const int lin2 = (lin & 7) * 512 + (lin >> 3);
    const int b   = lin2 >> 9;
    const int rem = lin2 & 511;
    const int by  = rem >> 3;      // 0..63
    const int bx  = rem & 7;       // 0..7
    const int x0t = bx * TX;
    const int y0t = by * TY;

    const int t = threadIdx.x;
    const int lane = t & 63;
    const int wv = t >> 6;         // wave 0..3 -> co-group
    const int l15 = lane & 15;
    const int cg = lane >> 4;      // 0..3

    // ---- stage x: 480 tasks (yl 6, q 10, cig 8), branchless (clamped loads)
#pragma unroll
    for (int it = 0; it < 2; ++it) {
        int n = t + it * 256;
        n = n < 479 ? n : 479;
        int cig = n & 7;
        int m = n >> 3;
        int q = m % 10;
        int yl = m / 10;            // 0..5
        int gy = y0t + yl - 1;      // -1..256
        int gx0 = x0t - 4 + q * 4;  // -4..256, 4-aligned
        bool rowok = (unsigned)gy < (unsigned)HH;
        int gyc  = gy < 0 ? 0 : (gy > HH - 1 ? HH - 1 : gy);
        int gx0c = gx0 < 0 ? 0 : (gx0 > WW - 4 ? WW - 4 : gx0);
        const float* xp = x + ((size_t)b * CC + cig * 8) * HW + (size_t)gyc * WW + gx0c;
        float4 v[8];
#pragma unroll
        for (int j = 0; j < 8; ++j)
            v[j] = *(const float4*)(xp + (size_t)j * HW);
#pragma unroll
        for (int k = 0; k < 4; ++k) {
            int lx = 4 * q - 3 + k;
            if ((unsigned)lx < (unsigned)LX) {
                bool ok = rowok && ((unsigned)(gx0 + k) < (unsigned)WW);
                uint4 w;
                w.x = ok ? pk2(VC(v[0], k), VC(v[1], k)) : 0u;
                w.y = ok ? pk2(VC(v[2], k), VC(v[3], k)) : 0u;
                w.z = ok ? pk2(VC(v[4], k), VC(v[5], k)) : 0u;
                w.w = ok ? pk2(VC(v[6], k), VC(v[7], k)) : 0u;
                unsigned off = ((unsigned)((yl * LX + lx) * 64 + cig * 8) * 2)
                               ^ ((unsigned)(lx & 7) << 4);
                *(uint4*)((char*)xs + off) = w;
            }
        }
    }

    floatx4 acc[8];
#pragma unroll
    for (int nt = 0; nt < 8; ++nt) acc[nt] = (floatx4)0.f;

    // ---- 3 kh-phases: stage weights -> barrier -> compute
#pragma unroll 1
    for (int kh = 0; kh < 3; ++kh) {
        __syncthreads();   // phase 0: x staged; phase >0: prev compute done
        // stage 3 kw-taps of weights: 12288 elems = 1536 uint4, 6 per thread
        {
            const unsigned short* wsrc = wbf + ((size_t)b * 9 + kh * 3) * 4096;
#pragma unroll
            for (int i = 0; i < 6; ++i) {
                int idx = t + i * 256;     // uint4 index, < 1536
                *(uint4*)&wlds[idx * 8] = *(const uint4*)&wsrc[idx * 8];
            }
        }
        __syncthreads();

#pragma unroll
        for (int kw = 0; kw < 3; ++kw) {
#pragma unroll
            for (int cic = 0; cic < 2; ++cic) {
                const short8 av = *(const short8*)&wlds[
                    (((kw * 2 + cic) * 4 + cg) * 64 + wv * 16 + l15) * 8];
#pragma unroll
                for (int nt = 0; nt < 8; ++nt) {
                    int r = nt >> 1, h = nt & 1;
                    int ys = r + kh;
                    int xl = h * 16 + l15 + kw;
                    unsigned off = ((unsigned)((ys * LX + xl) * 64 + cic * 32 + cg * 8) * 2)
                                   ^ ((unsigned)(xl & 7) << 4);
                    short8 bfr = *(const short8*)((const char*)xs + off);
                    acc[nt] = __builtin_amdgcn_mfma_f32_16x16x32_bf16(
                        av, bfr, acc[nt], 0, 0, 0);
                }
            }
        }
    }

    // ---- epilogue: noise + bias + leaky_relu * gain
    float nw = nwp[0];
    float bv[4];
#pragma unroll
    for (int j = 0; j < 4; ++j) bv[j] = bias[wv * 16 + cg * 4 + j];

#pragma unroll
    for (int nt = 0; nt < 8; ++nt) {
        int r = nt >> 1, h = nt & 1;
        int py = y0t + r;
        int px = x0t + h * 16 + l15;
        float nz = nw * noise[(size_t)b * HW + (size_t)py * WW + px];
#pragma unroll
        for (int j = 0; j < 4; ++j) {
            int co = wv * 16 + cg * 4 + j;
            float vv = acc[nt][j] + nz + bv[j];
            vv = (vv > 0.f ? vv : LRELU * vv) * GAIN;
            out[((size_t)b * CC + co) * HW + (size_t)py * WW + px] = vv;
        }
    }
}

extern "C" void kernel_launch(void* const* d_in, const int* in_sizes, int n_in,
                              void* d_out, int out_size, void* d_ws, size_t ws_size,
                              hipStream_t stream) {
    const float* x       = (const float*)d_in[0];
    const float* style   = (const float*)d_in[1];
    const float* noise   = (const float*)d_in[2];
    const float* weight  = (const float*)d_in[3];
    const float* mod_w   = (const float*)d_in[4];
    const float* mod_b   = (const float*)d_in[5];
    const float* nw      = (const float*)d_in[6];
    const float* bias    = (const float*)d_in[7];
    float* out = (float*)d_out;

    float* s_buf          = (float*)d_ws;                          // 2 KB
    unsigned short* wbf   = (unsigned short*)((char*)d_ws + 4096); // 576 KB

    mod_kernel<<<dim3(BB), dim3(256), 0, stream>>>(style, mod_w, mod_b, s_buf);
    wmod_kernel<<<dim3(BB * CC), dim3(CC), 0, stream>>>(weight, s_buf, wbf);
    conv_kernel<<<dim3((WW / TX) * (HH / TY) * BB), dim3(256), 0, stream>>>(
        x, noise, nw, bias, wbf, out);
}